// Round 3
// baseline (300.282 us; speedup 1.0000x reference)
//
#include <hip/hip_runtime.h>

// Problem dims (fixed by setup_inputs)
#define BB 16
#define CR 1024
#define HWD 784     // 28*28
#define HW2 392     // HWD/2 (float2 units)
#define CS 256
#define SSZ 25
#define SP 28       // padded row length for kk/M/v (112B = 7 x float4)
#define CI 512
#define CSPLIT 8    // c-chunks in energy (each 128)
#define CCHUNK 128
#define RSPLIT 32   // r-chunks in out (each 32)
#define RCHUNK 32

// Workspace layout (floats). Total = 3,842,704 floats ~= 15.4 MB.
// kk ([B][CI][SP] = 229376) aliases the head of Ep: last kk reader (k_e0)
// completes before first Ep writer (k_energy) by stream ordering.
#define OFF_POOLED 0          // [B][CS][S]        = 102400
#define OFF_VP     102400     // [B][CR][SP]       = 458752
#define OFF_MP     561152     // [B][CR][SP]       = 458752
#define OFF_E0     1019904    // [B][S]            = 400
#define OFF_ATT    1020304    // [B][S][HW]        = 313600
#define OFF_EP     1333904    // [CSPLIT][B][S][HW]= 2508800  (kk aliased at start)

// ---------------- K1: pooled = mean over width (rows of 25 floats) ----------------
__global__ __launch_bounds__(256) void k_pool(const float* __restrict__ xs,
                                              float* __restrict__ pooled) {
    __shared__ float buf[4][400];
    int wave = threadIdx.x >> 6, lane = threadIdx.x & 63;
    int r0 = blockIdx.x * 64 + wave * 16;          // 16 rows per wave
    const float4* src = (const float4*)(xs + (size_t)r0 * SSZ);   // 100 float4
    float4* b4 = (float4*)buf[wave];
    b4[lane] = src[lane];
    if (lane < 36) b4[64 + lane] = src[64 + lane];
    __syncthreads();
    if (lane < 16) {
        const float* row = buf[wave] + lane * SSZ;
        float s = 0.f;
#pragma unroll
        for (int w = 0; w < SSZ; ++w) s += row[w];
        pooled[r0 + lane] = s * (1.0f / SSZ);
    }
}

// ---------------- K2: kk = Wk*pooled + bk ; v = Wv*pooled + bv (K=256) ----------------
// lane = output row; per-lane weight-row float4 stream; pooled via uniform s_load.
// 4-way s-split: sh 0..2 -> 7 s each, sh 3 -> 4 s + zero pad.
template <int NS>
__device__ __forceinline__ void proj_body(const float* __restrict__ wrow,
                                          const float* __restrict__ pb, int s0,
                                          float bias, float* __restrict__ dst,
                                          bool zpad) {
    float acc[NS];
#pragma unroll
    for (int i = 0; i < NS; ++i) acc[i] = 0.f;
    const float4* w4 = (const float4*)wrow;
#pragma unroll 4
    for (int c4 = 0; c4 < CS / 4; ++c4) {
        float4 w = w4[c4];
        const float* p = pb + c4 * 4 * SSZ + s0;   // uniform -> s_load
#pragma unroll
        for (int i = 0; i < NS; ++i)
            acc[i] = fmaf(w.x, p[i],
                     fmaf(w.y, p[SSZ + i],
                     fmaf(w.z, p[2 * SSZ + i],
                     fmaf(w.w, p[3 * SSZ + i], acc[i]))));
    }
#pragma unroll
    for (int i = 0; i < NS; ++i) dst[s0 + i] = acc[i] + bias;
    if (zpad) { dst[25] = 0.f; dst[26] = 0.f; dst[27] = 0.f; }
}

__global__ __launch_bounds__(256) void k_kkv(const float* __restrict__ Wk,
                                             const float* __restrict__ Wv,
                                             const float* __restrict__ bk,
                                             const float* __restrict__ bv,
                                             const float* __restrict__ pooled,
                                             float* __restrict__ kk,
                                             float* __restrict__ vp) {
    int rb = blockIdx.x >> 2, sh = blockIdx.x & 3;   // rb 0..5, sh 0..3
    int b = blockIdx.y;
    const float* pb = pooled + (size_t)b * CS * SSZ;
    const float* wrow;
    float bias;
    float* dst;
    if (rb < 2) {               // kk rows: i = rb*256 + tid  (512 rows)
        int i = rb * 256 + threadIdx.x;
        wrow = Wk + (size_t)i * CS;
        bias = bk[i];
        dst = kk + ((size_t)b * CI + i) * SP;
    } else {                    // v rows: r = (rb-2)*256 + tid  (1024 rows)
        int r = (rb - 2) * 256 + threadIdx.x;
        wrow = Wv + (size_t)r * CS;
        bias = bv[r];
        dst = vp + ((size_t)b * CR + r) * SP;
    }
    int s0 = sh * 7;
    if (sh < 3) proj_body<7>(wrow, pb, s0, bias, dst, false);
    else        proj_body<4>(wrow, pb, s0, bias, dst, true);
}

// ---------------- K3: M[b][c][s] = sum_i Wq[i,c] * kk[b][i][s]  (K=512) ----------------
// lane = c -> Wq loads COALESCED (c is fast axis); kk rows uniform -> s_load.
template <int NS>
__device__ __forceinline__ void m_body(const float* __restrict__ Wq,
                                       const float* __restrict__ kkb, int c, int s0,
                                       float* __restrict__ dst, bool zpad) {
    float acc[NS];
#pragma unroll
    for (int i = 0; i < NS; ++i) acc[i] = 0.f;
#pragma unroll 4
    for (int i = 0; i < CI; ++i) {
        float w = Wq[(size_t)i * CR + c];           // coalesced
        const float* kr = kkb + i * SP + s0;        // uniform -> s_load
#pragma unroll
        for (int j = 0; j < NS; ++j) acc[j] = fmaf(w, kr[j], acc[j]);
    }
#pragma unroll
    for (int j = 0; j < NS; ++j) dst[s0 + j] = acc[j];
    if (zpad) { dst[25] = 0.f; dst[26] = 0.f; dst[27] = 0.f; }
}

__global__ __launch_bounds__(256) void k_M(const float* __restrict__ Wq,
                                           const float* __restrict__ kk,
                                           float* __restrict__ Mp) {
    int cblk = blockIdx.x >> 2, sh = blockIdx.x & 3;
    int b = blockIdx.y;
    int c = cblk * 256 + threadIdx.x;
    const float* kkb = kk + (size_t)b * CI * SP;
    float* dst = Mp + ((size_t)b * CR + c) * SP;
    int s0 = sh * 7;
    if (sh < 3) m_body<7>(Wq, kkb, c, s0, dst, false);
    else        m_body<4>(Wq, kkb, c, s0, dst, true);
}

// ---------------- K3b: e0[b][s] = sum_i bq[i] * kk[b][i][s] ----------------
__global__ __launch_bounds__(256) void k_e0(const float* __restrict__ bq,
                                            const float* __restrict__ kk,
                                            float* __restrict__ e0) {
    int t = blockIdx.x * 256 + threadIdx.x;
    if (t >= BB * SSZ) return;
    int b = t / SSZ, s = t % SSZ;
    const float* kb = kk + (size_t)b * CI * SP + s;
    float a = 0.f;
#pragma unroll 4
    for (int i = 0; i < CI; ++i) a = fmaf(bq[i], kb[(size_t)i * SP], a);
    e0[t] = a;
}

// ---------------- K4: partial energies Ep[ch][b][s][n], float2 lanes ----------------
// M chunk (128 x 28) staged in LDS; x loads batched 4-deep for latency hiding.
__global__ __launch_bounds__(64) void k_energy(const float* __restrict__ xr,
                                               const float* __restrict__ Mp,
                                               float* __restrict__ Ep) {
    __shared__ float ldsM[CCHUNK * SP];            // 14336 B
    int lane = threadIdx.x;
    int b = blockIdx.y, ch = blockIdx.z;
    int cbeg = ch * CCHUNK;
    {
        const float4* src = (const float4*)(Mp + ((size_t)b * CR + cbeg) * SP);
        float4* dst = (float4*)ldsM;
#pragma unroll
        for (int j = 0; j < 14; ++j) dst[lane + 64 * j] = src[lane + 64 * j];
    }
    __syncthreads();

    int n2 = blockIdx.x * 64 + lane;
    bool valid = n2 < HW2;
    int n2c = valid ? n2 : 0;
    const float2* x2 = (const float2*)(xr + (size_t)b * CR * HWD);

    float acc0[SP], acc1[SP];
#pragma unroll
    for (int s = 0; s < SP; ++s) { acc0[s] = 0.f; acc1[s] = 0.f; }

    for (int c = 0; c < CCHUNK; c += 4) {
        float2 xv[4];
#pragma unroll
        for (int u = 0; u < 4; ++u)
            xv[u] = x2[(size_t)(cbeg + c + u) * HW2 + n2c];   // 4 loads in flight
#pragma unroll
        for (int u = 0; u < 4; ++u) {
            const float4* mr = (const float4*)&ldsM[(c + u) * SP];
#pragma unroll
            for (int j = 0; j < 7; ++j) {
                float4 m = mr[j];
                acc0[4 * j + 0] = fmaf(xv[u].x, m.x, acc0[4 * j + 0]);
                acc0[4 * j + 1] = fmaf(xv[u].x, m.y, acc0[4 * j + 1]);
                acc0[4 * j + 2] = fmaf(xv[u].x, m.z, acc0[4 * j + 2]);
                acc0[4 * j + 3] = fmaf(xv[u].x, m.w, acc0[4 * j + 3]);
                acc1[4 * j + 0] = fmaf(xv[u].y, m.x, acc1[4 * j + 0]);
                acc1[4 * j + 1] = fmaf(xv[u].y, m.y, acc1[4 * j + 1]);
                acc1[4 * j + 2] = fmaf(xv[u].y, m.z, acc1[4 * j + 2]);
                acc1[4 * j + 3] = fmaf(xv[u].y, m.w, acc1[4 * j + 3]);
            }
        }
    }
    if (valid) {
        float2* ep = (float2*)Ep + ((size_t)(ch * BB + b) * SSZ) * HW2 + n2;
#pragma unroll
        for (int s = 0; s < SSZ; ++s) ep[(size_t)s * HW2] = make_float2(acc0[s], acc1[s]);
    }
}

// ---------------- K4b: att = softmax_s(sum_ch Ep + e0), float2 lanes ----------------
__global__ __launch_bounds__(64) void k_softmax(const float* __restrict__ Ep,
                                                const float* __restrict__ e0,
                                                float* __restrict__ att) {
    int lane = threadIdx.x;
    int n2 = blockIdx.x * 64 + lane;
    int b = blockIdx.y;
    if (n2 >= HW2) return;
    float ex[SSZ], ey[SSZ];
#pragma unroll
    for (int s = 0; s < SSZ; ++s) { float v = e0[b * SSZ + s]; ex[s] = v; ey[s] = v; }
    const float2* ep2 = (const float2*)Ep;
    for (int ch = 0; ch < CSPLIT; ++ch) {
        const float2* ep = ep2 + ((size_t)(ch * BB + b) * SSZ) * HW2 + n2;
#pragma unroll
        for (int s = 0; s < SSZ; ++s) {
            float2 v = ep[(size_t)s * HW2];
            ex[s] += v.x; ey[s] += v.y;
        }
    }
    float mx = ex[0], my = ey[0];
#pragma unroll
    for (int s = 1; s < SSZ; ++s) { mx = fmaxf(mx, ex[s]); my = fmaxf(my, ey[s]); }
    float sx = 0.f, sy = 0.f;
#pragma unroll
    for (int s = 0; s < SSZ; ++s) {
        ex[s] = __expf(ex[s] - mx); sx += ex[s];
        ey[s] = __expf(ey[s] - my); sy += ey[s];
    }
    float ix = 1.0f / sx, iy = 1.0f / sy;
    float2* ao = (float2*)att + ((size_t)b * SSZ) * HW2 + n2;
#pragma unroll
    for (int s = 0; s < SSZ; ++s) ao[(size_t)s * HW2] = make_float2(ex[s] * ix, ey[s] * iy);
}

// ---------------- K5: out = gamma * (v·att) + x_rgb, float2 lanes ----------------
__global__ __launch_bounds__(64) void k_out(const float* __restrict__ xr,
                                            const float* __restrict__ vp,
                                            const float* __restrict__ att,
                                            const float* __restrict__ gamma,
                                            float* __restrict__ out) {
    __shared__ float ldsv[RCHUNK * SP];            // 3584 B
    int lane = threadIdx.x;
    int b = blockIdx.y, rz = blockIdx.z;
    int r0 = rz * RCHUNK;
    {
        const float4* src = (const float4*)(vp + ((size_t)b * CR + r0) * SP);
        float4* dst = (float4*)ldsv;
#pragma unroll
        for (int j = 0; j < 4; ++j) {
            int idx = lane + 64 * j;
            if (idx < RCHUNK * SP / 4) dst[idx] = src[idx];
        }
    }
    __syncthreads();

    int n2 = blockIdx.x * 64 + lane;
    bool valid = n2 < HW2;
    int n2c = valid ? n2 : 0;

    float a0[SP], a1[SP];
    const float2* at2 = (const float2*)att + ((size_t)b * SSZ) * HW2 + n2c;
#pragma unroll
    for (int s = 0; s < SSZ; ++s) {
        float2 av = at2[(size_t)s * HW2];
        a0[s] = av.x; a1[s] = av.y;
    }
#pragma unroll
    for (int s = SSZ; s < SP; ++s) { a0[s] = 0.f; a1[s] = 0.f; }

    float g = gamma[0];
    const float2* x2 = (const float2*)(xr + (size_t)b * CR * HWD);
    float2* o2 = (float2*)(out + (size_t)b * CR * HWD);

#pragma unroll 4
    for (int r = 0; r < RCHUNK; ++r) {
        float2 xv = x2[(size_t)(r0 + r) * HW2 + n2c];
        float d0 = 0.f, d1 = 0.f;
        const float4* vr = (const float4*)&ldsv[r * SP];
#pragma unroll
        for (int j = 0; j < 7; ++j) {
            float4 v = vr[j];
            d0 = fmaf(v.x, a0[4 * j + 0], d0);
            d0 = fmaf(v.y, a0[4 * j + 1], d0);
            d0 = fmaf(v.z, a0[4 * j + 2], d0);
            d0 = fmaf(v.w, a0[4 * j + 3], d0);
            d1 = fmaf(v.x, a1[4 * j + 0], d1);
            d1 = fmaf(v.y, a1[4 * j + 1], d1);
            d1 = fmaf(v.z, a1[4 * j + 2], d1);
            d1 = fmaf(v.w, a1[4 * j + 3], d1);
        }
        if (valid)
            o2[(size_t)(r0 + r) * HW2 + n2] = make_float2(fmaf(g, d0, xv.x), fmaf(g, d1, xv.y));
    }
}

extern "C" void kernel_launch(void* const* d_in, const int* in_sizes, int n_in,
                              void* d_out, int out_size, void* d_ws, size_t ws_size,
                              hipStream_t stream) {
    const float* x_rgb  = (const float*)d_in[0];
    const float* x_skel = (const float*)d_in[1];
    const float* Wq     = (const float*)d_in[2];
    const float* bq     = (const float*)d_in[3];
    const float* Wk     = (const float*)d_in[4];
    const float* bk     = (const float*)d_in[5];
    const float* Wv     = (const float*)d_in[6];
    const float* bv     = (const float*)d_in[7];
    const float* gamma  = (const float*)d_in[8];
    float* out = (float*)d_out;

    float* ws     = (float*)d_ws;
    float* pooled = ws + OFF_POOLED;
    float* vp     = ws + OFF_VP;
    float* Mp     = ws + OFF_MP;
    float* e0     = ws + OFF_E0;
    float* att    = ws + OFF_ATT;
    float* Ep     = ws + OFF_EP;
    float* kk     = ws + OFF_EP;   // alias: kk dead before Ep written

    k_pool   <<<dim3(1600),           256, 0, stream>>>(x_skel, pooled);
    k_kkv    <<<dim3(24, 16),         256, 0, stream>>>(Wk, Wv, bk, bv, pooled, kk, vp);
    k_M      <<<dim3(16, 16),         256, 0, stream>>>(Wq, kk, Mp);
    k_e0     <<<dim3(2),              256, 0, stream>>>(bq, kk, e0);
    k_energy <<<dim3(7, 16, CSPLIT),   64, 0, stream>>>(x_rgb, Mp, Ep);
    k_softmax<<<dim3(7, 16),           64, 0, stream>>>(Ep, e0, att);
    k_out    <<<dim3(7, 16, RSPLIT),   64, 0, stream>>>(x_rgb, vp, att, gamma, out);
}

// Round 4
// 233.248 us; speedup vs baseline: 1.2874x; 1.2874x over previous
//
#include <hip/hip_runtime.h>

// Problem dims (fixed by setup_inputs)
#define BB 16
#define CR 1024
#define HWD 784     // 28*28
#define HW2 392     // HWD/2 (float2 units)
#define CS 256
#define SSZ 25
#define SP 28       // padded row length for kk/M/v (112B = 7 x float4)
#define CI 512
#define CSPLIT 8    // c-chunks in energy (each 128)
#define CCHUNK 128
#define RSPLIT 32   // r-chunks in out (each 32)
#define RCHUNK 32
#define KC 4        // K-split for M partials (128 i each)

// Workspace layout (floats). Total = 3,842,704 floats ~= 15.4 MB.
// Ep region is time-shared: [kk (229376) | P (1835008)] live before k_energy;
// both dead by the time k_energy writes Ep (stream ordering).
#define OFF_POOLED 0          // [B][CS][S]        = 102400
#define OFF_VP     102400     // [B][CR][SP]       = 458752
#define OFF_MP     561152     // [B][CR][SP]       = 458752
#define OFF_E0     1019904    // [B][S]            = 400
#define OFF_ATT    1020304    // [B][S][HW]        = 313600
#define OFF_EP     1333904    // [CSPLIT][B][S][HW]= 2508800
#define OFF_KK     1333904    // alias: [B][CI][SP] = 229376
#define OFF_P      1563280    // alias: [KC][B][4sh][256t][28] = 1835008

// ---------------- K1: pooled = mean over width (rows of 25 floats) ----------------
__global__ __launch_bounds__(256) void k_pool(const float* __restrict__ xs,
                                              float* __restrict__ pooled) {
    __shared__ float buf[4][400];
    int wave = threadIdx.x >> 6, lane = threadIdx.x & 63;
    int r0 = blockIdx.x * 64 + wave * 16;          // 16 rows per wave
    const float4* src = (const float4*)(xs + (size_t)r0 * SSZ);   // 100 float4
    float4* b4 = (float4*)buf[wave];
    b4[lane] = src[lane];
    if (lane < 36) b4[64 + lane] = src[64 + lane];
    __syncthreads();
    if (lane < 16) {
        const float* row = buf[wave] + lane * SSZ;
        float s = 0.f;
#pragma unroll
        for (int w = 0; w < SSZ; ++w) s += row[w];
        pooled[r0 + lane] = s * (1.0f / SSZ);
    }
}

// ---------------- K2: kk = Wk*pooled + bk ; v = Wv*pooled + bv (K=256) ----------------
template <int NS>
__device__ __forceinline__ void proj_body(const float* __restrict__ wrow,
                                          const float* __restrict__ pb, int s0,
                                          float bias, float* __restrict__ dst,
                                          bool zpad) {
    float acc[NS];
#pragma unroll
    for (int i = 0; i < NS; ++i) acc[i] = 0.f;
    const float4* w4 = (const float4*)wrow;
#pragma unroll 4
    for (int c4 = 0; c4 < CS / 4; ++c4) {
        float4 w = w4[c4];
        const float* p = pb + c4 * 4 * SSZ + s0;   // uniform -> s_load
#pragma unroll
        for (int i = 0; i < NS; ++i)
            acc[i] = fmaf(w.x, p[i],
                     fmaf(w.y, p[SSZ + i],
                     fmaf(w.z, p[2 * SSZ + i],
                     fmaf(w.w, p[3 * SSZ + i], acc[i]))));
    }
#pragma unroll
    for (int i = 0; i < NS; ++i) dst[s0 + i] = acc[i] + bias;
    if (zpad) { dst[25] = 0.f; dst[26] = 0.f; dst[27] = 0.f; }
}

__global__ __launch_bounds__(256) void k_kkv(const float* __restrict__ Wk,
                                             const float* __restrict__ Wv,
                                             const float* __restrict__ bk,
                                             const float* __restrict__ bv,
                                             const float* __restrict__ pooled,
                                             float* __restrict__ kk,
                                             float* __restrict__ vp) {
    int rb = blockIdx.x >> 2, sh = blockIdx.x & 3;   // rb 0..5, sh 0..3
    int b = blockIdx.y;
    const float* pb = pooled + (size_t)b * CS * SSZ;
    const float* wrow;
    float bias;
    float* dst;
    if (rb < 2) {               // kk rows: i = rb*256 + tid  (512 rows)
        int i = rb * 256 + threadIdx.x;
        wrow = Wk + (size_t)i * CS;
        bias = bk[i];
        dst = kk + ((size_t)b * CI + i) * SP;
    } else {                    // v rows: r = (rb-2)*256 + tid  (1024 rows)
        int r = (rb - 2) * 256 + threadIdx.x;
        wrow = Wv + (size_t)r * CS;
        bias = bv[r];
        dst = vp + ((size_t)b * CR + r) * SP;
    }
    int s0 = sh * 7;
    if (sh < 3) proj_body<7>(wrow, pb, s0, bias, dst, false);
    else        proj_body<4>(wrow, pb, s0, bias, dst, true);
}

// ---------------- K3a: M partials via LDS-broadcast GEMM ----------------
// P[kc][b][sh][t][28]: thread t's 4c x 7s tile, contiguous 28 floats.
// Inner loop per i: 1 coalesced float4 Wq load + 2 broadcast ds_read_b128 + 28 FMA.
__global__ __launch_bounds__(256) void k_Mpart(const float* __restrict__ Wq,
                                               const float* __restrict__ kk,
                                               float* __restrict__ P) {
    __shared__ __align__(16) float lds[128 * 8];   // kk[i-chunk][s-slice(7)+1]
    int sh = blockIdx.x, kc = blockIdx.y, b = blockIdx.z;
    int t = threadIdx.x;
    int s0 = sh * 7;
    int i0 = kc * 128;
    const float* kkb = kk + (size_t)b * CI * SP;
    // stage kk[i0..i0+127][s0..s0+7] -> lds[row*8+col]  (col 7 is slack, never used in FMA)
#pragma unroll
    for (int q = 0; q < 4; ++q) {
        int d = t + 256 * q;                       // 0..1023; row=d>>3, col=d&7
        lds[d] = kkb[(size_t)(i0 + (d >> 3)) * SP + s0 + (d & 7)];
    }
    __syncthreads();

    float acc[28];
#pragma unroll
    for (int e = 0; e < 28; ++e) acc[e] = 0.f;
    const float4* lds4 = (const float4*)lds;
#pragma unroll 4
    for (int i = 0; i < 128; ++i) {
        float4 w = *(const float4*)(Wq + (size_t)(i0 + i) * CR + 4 * t);  // coalesced
        float4 k0 = lds4[i * 2];                   // s0..s0+3 (broadcast)
        float4 k1 = lds4[i * 2 + 1];               // s0+4..s0+6 (+slack)
#pragma unroll
        for (int j = 0; j < 4; ++j) {
            float wj = j == 0 ? w.x : j == 1 ? w.y : j == 2 ? w.z : w.w;
            acc[j * 7 + 0] = fmaf(wj, k0.x, acc[j * 7 + 0]);
            acc[j * 7 + 1] = fmaf(wj, k0.y, acc[j * 7 + 1]);
            acc[j * 7 + 2] = fmaf(wj, k0.z, acc[j * 7 + 2]);
            acc[j * 7 + 3] = fmaf(wj, k0.w, acc[j * 7 + 3]);
            acc[j * 7 + 4] = fmaf(wj, k1.x, acc[j * 7 + 4]);
            acc[j * 7 + 5] = fmaf(wj, k1.y, acc[j * 7 + 5]);
            acc[j * 7 + 6] = fmaf(wj, k1.z, acc[j * 7 + 6]);
        }
    }
    float* dst = P + ((((size_t)kc * BB + b) * 4 + sh) * 256 + t) * 28;
#pragma unroll
    for (int m = 0; m < 7; ++m) {
        float4 o;
        o.x = acc[4 * m + 0]; o.y = acc[4 * m + 1];
        o.z = acc[4 * m + 2]; o.w = acc[4 * m + 3];
        *(float4*)(dst + 4 * m) = o;               // contiguous 28 per thread
    }
}

// ---------------- K3b: Mp[b][c][s] = sum_kc P ----------------
__global__ __launch_bounds__(256) void k_Mred(const float* __restrict__ P,
                                              float* __restrict__ Mp) {
    int id = blockIdx.x * 256 + threadIdx.x;       // 16384 = b*4sh*256t
    int t = id & 255, sh = (id >> 8) & 3, b = id >> 10;
    const float* p0 = P + ((((size_t)b) * 4 + sh) * 256 + t) * 28;
    const size_t PL = (size_t)BB * 4 * 256 * 28;   // 458752 per kc-plane
    float v[28];
#pragma unroll
    for (int m = 0; m < 7; ++m) {
        float4 a = *(const float4*)(p0 + 4 * m);
        float4 b1 = *(const float4*)(p0 + PL + 4 * m);
        float4 c = *(const float4*)(p0 + 2 * PL + 4 * m);
        float4 d = *(const float4*)(p0 + 3 * PL + 4 * m);
        v[4 * m + 0] = a.x + b1.x + c.x + d.x;
        v[4 * m + 1] = a.y + b1.y + c.y + d.y;
        v[4 * m + 2] = a.z + b1.z + c.z + d.z;
        v[4 * m + 3] = a.w + b1.w + c.w + d.w;
    }
    int s0 = sh * 7;
    float* mb = Mp + ((size_t)b * CR + 4 * t) * SP + s0;
#pragma unroll
    for (int j = 0; j < 4; ++j)
#pragma unroll
        for (int u = 0; u < 7; ++u)
            mb[j * SP + u] = v[j * 7 + u];
}

// ---------------- K3c: e0[b][s] = sum_i bq[i]*kk[b][i][s] (wave reduction) ----------------
__global__ __launch_bounds__(64) void k_e0(const float* __restrict__ bq,
                                           const float* __restrict__ kk,
                                           float* __restrict__ e0) {
    int s = blockIdx.x, b = blockIdx.y;
    int l = threadIdx.x;
    const float* kb = kk + (size_t)b * CI * SP;
    float a = 0.f;
#pragma unroll
    for (int k = 0; k < CI / 64; ++k) {
        int i = l + 64 * k;
        a = fmaf(bq[i], kb[(size_t)i * SP + s], a);
    }
#pragma unroll
    for (int off = 32; off > 0; off >>= 1) a += __shfl_down(a, off);
    if (l == 0) e0[b * SSZ + s] = a;
}

// ---------------- K4: partial energies Ep[ch][b][s][n], float2 lanes ----------------
__global__ __launch_bounds__(64) void k_energy(const float* __restrict__ xr,
                                               const float* __restrict__ Mp,
                                               float* __restrict__ Ep) {
    __shared__ float ldsM[CCHUNK * SP];            // 14336 B
    int lane = threadIdx.x;
    int b = blockIdx.y, ch = blockIdx.z;
    int cbeg = ch * CCHUNK;
    {
        const float4* src = (const float4*)(Mp + ((size_t)b * CR + cbeg) * SP);
        float4* dst = (float4*)ldsM;
#pragma unroll
        for (int j = 0; j < 14; ++j) dst[lane + 64 * j] = src[lane + 64 * j];
    }
    __syncthreads();

    int n2 = blockIdx.x * 64 + lane;
    bool valid = n2 < HW2;
    int n2c = valid ? n2 : 0;
    const float2* x2 = (const float2*)(xr + (size_t)b * CR * HWD);

    float acc0[SP], acc1[SP];
#pragma unroll
    for (int s = 0; s < SP; ++s) { acc0[s] = 0.f; acc1[s] = 0.f; }

    for (int c = 0; c < CCHUNK; c += 4) {
        float2 xv[4];
#pragma unroll
        for (int u = 0; u < 4; ++u)
            xv[u] = x2[(size_t)(cbeg + c + u) * HW2 + n2c];   // 4 loads in flight
#pragma unroll
        for (int u = 0; u < 4; ++u) {
            const float4* mr = (const float4*)&ldsM[(c + u) * SP];
#pragma unroll
            for (int j = 0; j < 7; ++j) {
                float4 m = mr[j];
                acc0[4 * j + 0] = fmaf(xv[u].x, m.x, acc0[4 * j + 0]);
                acc0[4 * j + 1] = fmaf(xv[u].x, m.y, acc0[4 * j + 1]);
                acc0[4 * j + 2] = fmaf(xv[u].x, m.z, acc0[4 * j + 2]);
                acc0[4 * j + 3] = fmaf(xv[u].x, m.w, acc0[4 * j + 3]);
                acc1[4 * j + 0] = fmaf(xv[u].y, m.x, acc1[4 * j + 0]);
                acc1[4 * j + 1] = fmaf(xv[u].y, m.y, acc1[4 * j + 1]);
                acc1[4 * j + 2] = fmaf(xv[u].y, m.z, acc1[4 * j + 2]);
                acc1[4 * j + 3] = fmaf(xv[u].y, m.w, acc1[4 * j + 3]);
            }
        }
    }
    if (valid) {
        float2* ep = (float2*)Ep + ((size_t)(ch * BB + b) * SSZ) * HW2 + n2;
#pragma unroll
        for (int s = 0; s < SSZ; ++s) ep[(size_t)s * HW2] = make_float2(acc0[s], acc1[s]);
    }
}

// ---------------- K4b: att = softmax_s(sum_ch Ep + e0), float2 lanes ----------------
__global__ __launch_bounds__(64) void k_softmax(const float* __restrict__ Ep,
                                                const float* __restrict__ e0,
                                                float* __restrict__ att) {
    int lane = threadIdx.x;
    int n2 = blockIdx.x * 64 + lane;
    int b = blockIdx.y;
    if (n2 >= HW2) return;
    float ex[SSZ], ey[SSZ];
#pragma unroll
    for (int s = 0; s < SSZ; ++s) { float v = e0[b * SSZ + s]; ex[s] = v; ey[s] = v; }
    const float2* ep2 = (const float2*)Ep;
    for (int ch = 0; ch < CSPLIT; ++ch) {
        const float2* ep = ep2 + ((size_t)(ch * BB + b) * SSZ) * HW2 + n2;
#pragma unroll
        for (int s = 0; s < SSZ; ++s) {
            float2 v = ep[(size_t)s * HW2];
            ex[s] += v.x; ey[s] += v.y;
        }
    }
    float mx = ex[0], my = ey[0];
#pragma unroll
    for (int s = 1; s < SSZ; ++s) { mx = fmaxf(mx, ex[s]); my = fmaxf(my, ey[s]); }
    float sx = 0.f, sy = 0.f;
#pragma unroll
    for (int s = 0; s < SSZ; ++s) {
        ex[s] = __expf(ex[s] - mx); sx += ex[s];
        ey[s] = __expf(ey[s] - my); sy += ey[s];
    }
    float ix = 1.0f / sx, iy = 1.0f / sy;
    float2* ao = (float2*)att + ((size_t)b * SSZ) * HW2 + n2;
#pragma unroll
    for (int s = 0; s < SSZ; ++s) ao[(size_t)s * HW2] = make_float2(ex[s] * ix, ey[s] * iy);
}

// ---------------- K5: out = gamma * (v·att) + x_rgb, float2 lanes ----------------
__global__ __launch_bounds__(64) void k_out(const float* __restrict__ xr,
                                            const float* __restrict__ vp,
                                            const float* __restrict__ att,
                                            const float* __restrict__ gamma,
                                            float* __restrict__ out) {
    __shared__ float ldsv[RCHUNK * SP];            // 3584 B
    int lane = threadIdx.x;
    int b = blockIdx.y, rz = blockIdx.z;
    int r0 = rz * RCHUNK;
    {
        const float4* src = (const float4*)(vp + ((size_t)b * CR + r0) * SP);
        float4* dst = (float4*)ldsv;
#pragma unroll
        for (int j = 0; j < 4; ++j) {
            int idx = lane + 64 * j;
            if (idx < RCHUNK * SP / 4) dst[idx] = src[idx];
        }
    }
    __syncthreads();

    int n2 = blockIdx.x * 64 + lane;
    bool valid = n2 < HW2;
    int n2c = valid ? n2 : 0;

    float a0[SP], a1[SP];
    const float2* at2 = (const float2*)att + ((size_t)b * SSZ) * HW2 + n2c;
#pragma unroll
    for (int s = 0; s < SSZ; ++s) {
        float2 av = at2[(size_t)s * HW2];
        a0[s] = av.x; a1[s] = av.y;
    }
#pragma unroll
    for (int s = SSZ; s < SP; ++s) { a0[s] = 0.f; a1[s] = 0.f; }

    float g = gamma[0];
    const float2* x2 = (const float2*)(xr + (size_t)b * CR * HWD);
    float2* o2 = (float2*)(out + (size_t)b * CR * HWD);

#pragma unroll 4
    for (int r = 0; r < RCHUNK; ++r) {
        float2 xv = x2[(size_t)(r0 + r) * HW2 + n2c];
        float d0 = 0.f, d1 = 0.f;
        const float4* vr = (const float4*)&ldsv[r * SP];
#pragma unroll
        for (int j = 0; j < 7; ++j) {
            float4 v = vr[j];
            d0 = fmaf(v.x, a0[4 * j + 0], d0);
            d0 = fmaf(v.y, a0[4 * j + 1], d0);
            d0 = fmaf(v.z, a0[4 * j + 2], d0);
            d0 = fmaf(v.w, a0[4 * j + 3], d0);
            d1 = fmaf(v.x, a1[4 * j + 0], d1);
            d1 = fmaf(v.y, a1[4 * j + 1], d1);
            d1 = fmaf(v.z, a1[4 * j + 2], d1);
            d1 = fmaf(v.w, a1[4 * j + 3], d1);
        }
        if (valid)
            o2[(size_t)(r0 + r) * HW2 + n2] = make_float2(fmaf(g, d0, xv.x), fmaf(g, d1, xv.y));
    }
}

extern "C" void kernel_launch(void* const* d_in, const int* in_sizes, int n_in,
                              void* d_out, int out_size, void* d_ws, size_t ws_size,
                              hipStream_t stream) {
    const float* x_rgb  = (const float*)d_in[0];
    const float* x_skel = (const float*)d_in[1];
    const float* Wq     = (const float*)d_in[2];
    const float* bq     = (const float*)d_in[3];
    const float* Wk     = (const float*)d_in[4];
    const float* bk     = (const float*)d_in[5];
    const float* Wv     = (const float*)d_in[6];
    const float* bv     = (const float*)d_in[7];
    const float* gamma  = (const float*)d_in[8];
    float* out = (float*)d_out;

    float* ws     = (float*)d_ws;
    float* pooled = ws + OFF_POOLED;
    float* vp     = ws + OFF_VP;
    float* Mp     = ws + OFF_MP;
    float* e0     = ws + OFF_E0;
    float* att    = ws + OFF_ATT;
    float* Ep     = ws + OFF_EP;
    float* kk     = ws + OFF_KK;   // alias into Ep region
    float* P      = ws + OFF_P;    // alias into Ep region

    k_pool   <<<dim3(1600),           256, 0, stream>>>(x_skel, pooled);
    k_kkv    <<<dim3(24, 16),         256, 0, stream>>>(Wk, Wv, bk, bv, pooled, kk, vp);
    k_Mpart  <<<dim3(4, KC, 16),      256, 0, stream>>>(Wq, kk, P);
    k_Mred   <<<dim3(64),             256, 0, stream>>>(P, Mp);
    k_e0     <<<dim3(25, 16),          64, 0, stream>>>(bq, kk, e0);
    k_energy <<<dim3(7, 16, CSPLIT),   64, 0, stream>>>(x_rgb, Mp, Ep);
    k_softmax<<<dim3(7, 16),           64, 0, stream>>>(Ep, e0, att);
    k_out    <<<dim3(7, 16, RSPLIT),   64, 0, stream>>>(x_rgb, vp, att, gamma, out);
}